// Round 9
// baseline (391.314 us; speedup 1.0000x reference)
//
#include <hip/hip_runtime.h>
#include <hip/hip_fp16.h>
#include <math.h>

typedef _Float16 h16_t;
typedef __attribute__((ext_vector_type(4))) _Float16 h16x4;
typedef __attribute__((ext_vector_type(8))) _Float16 h16x8;
typedef __attribute__((ext_vector_type(4))) float f32x4;

static_assert(sizeof(h16_t) == 2, "f16 size");

__device__ __forceinline__ f32x4 mfma16(h16x8 a, h16x8 b, f32x4 c) {
  return __builtin_amdgcn_mfma_f32_16x16x32_f16(a, b, c, 0, 0, 0);
}

// ---------------------------------------------------------------------------
// MERGED: fused f32->f16 conversion (10 segments) || ck/cv colnorm phase 1.
// ---------------------------------------------------------------------------
struct CvtArgs {
  const float* src[10];
  h16_t* dst[10];
  int start4[10];
  int total4;
  int nblk_cvt;
  const float* c0;
  const float* c1;
  float* part;
};

__global__ __launch_bounds__(384) void k_cvt_p1(CvtArgs a) {
  const int bid = blockIdx.x;
  if (bid < a.nblk_cvt) {  // --- cvt path ---
    const int i4 = bid * 384 + threadIdx.x;
    if (i4 >= a.total4) return;
    int seg = 0;
#pragma unroll
    for (int t = 1; t < 10; ++t) seg += (i4 >= a.start4[t]) ? 1 : 0;
    const int off = (i4 - a.start4[seg]) * 4;
    const float4 v = *(const float4*)(a.src[seg] + off);
    h16x4 o;
    o[0] = (h16_t)v.x; o[1] = (h16_t)v.y; o[2] = (h16_t)v.z; o[3] = (h16_t)v.w;
    *(h16x4*)(a.dst[seg] + off) = o;
  } else {  // --- cn_ck_p1 path ---
    const int rid = bid - a.nblk_cvt;
    const int b = rid & 7, ch = (rid >> 3) & 63, z = rid >> 9;
    const int f = threadIdx.x;
    const float* c = z ? a.c1 : a.c0;
    const int h = f >> 6, d = f & 63;
    const float* p = c + ((size_t)(b * 6 + h) * 1024 + ch * 16) * 64 + d;
    float s = 0.f;
#pragma unroll
    for (int n = 0; n < 16; ++n) {
      const float v = p[(size_t)n * 64];
      s += v * v;
    }
    a.part[(size_t)z * 196608 + (size_t)(b * 64 + ch) * 384 + f] = s;
  }
}

// ---------------------------------------------------------------------------
// GEMM core: W staged through DOUBLE-BUFFERED 128-col segments (2x16KB LDS).
// ---------------------------------------------------------------------------
template <int K>
__device__ __forceinline__ void gemm_run(const h16_t* __restrict__ A,
                                         const h16_t* __restrict__ W,
                                         int m0, int o0, h16_t* wl, f32x4* acc) {
  constexpr int NS = K / 128;
  const int lane = threadIdx.x & 63;
  const int l15 = lane & 15;
  const int quad = lane >> 4;
  int sr[4], sc[4], sd[4];
#pragma unroll
  for (int i = 0; i < 4; ++i) {
    const int id = threadIdx.x + i * 256;
    const int row = id >> 4, c = id & 15;
    sr[i] = row;
    sc[i] = c * 8;
    sd[i] = (row * 16 + (c ^ (row & 7))) * 8;
  }
  h16x8 wr[4];
#pragma unroll
  for (int i = 0; i < 4; ++i)
    wr[i] = *(const h16x8*)(W + (size_t)(o0 + sr[i]) * K + sc[i]);
#pragma unroll
  for (int i = 0; i < 4; ++i) *(h16x8*)(wl + sd[i]) = wr[i];
  __syncthreads();
#pragma unroll
  for (int sg = 0; sg < NS; ++sg) {
    if (sg + 1 < NS) {
#pragma unroll
      for (int i = 0; i < 4; ++i)
        wr[i] = *(const h16x8*)(W + (size_t)(o0 + sr[i]) * K + (sg + 1) * 128 + sc[i]);
    }
    const h16_t* ap = A + (size_t)(m0 + l15) * K + sg * 128 + quad * 8;
    const h16_t* wp = wl + (sg & 1) * 8192;
#pragma unroll
    for (int ks = 0; ks < 4; ++ks) {
      h16x8 af = *(const h16x8*)(ap + ks * 32);
#pragma unroll
      for (int j = 0; j < 4; ++j) {
        h16x8 wf = *(const h16x8*)(
            wp + (size_t)((j * 16 + l15) * 16 + ((ks * 4 + quad) ^ (l15 & 7))) * 8);
        acc[j] = mfma16(af, wf, acc[j]);
      }
    }
    if (sg + 1 < NS) {
      h16_t* wn = wl + ((sg + 1) & 1) * 8192;
#pragma unroll
      for (int i = 0; i < 4; ++i) *(h16x8*)(wn + sd[i]) = wr[i];
    }
    __syncthreads();
  }
}

#define EPILOGUE_SETUP()                            \
  const int wv = threadIdx.x >> 6;                  \
  const int lane = threadIdx.x & 63;                \
  const int l15 = lane & 15;                        \
  const int quad = lane >> 4;                       \
  const int m0 = blockIdx.x * 64 + wv * 16;         \
  const int o0 = blockIdx.y * 64;                   \
  f32x4 acc[4];                                     \
  for (int j = 0; j < 4; ++j) acc[j] = f32x4{0.f, 0.f, 0.f, 0.f};

struct Leaky2Args {
  const h16_t* A0; const h16_t* W0; const float* b0; h16_t* Y0;
  const h16_t* A1; const h16_t* W1; const float* b1; h16_t* Y1;
};

// LeakyReLU GEMM, z-merged. LAYOUT: 0 row-major; 1 (b,h,n,d); 2 (b,h,d,n)
template <int K, int L0, int L1>
__global__ __launch_bounds__(256) void k_gemm_leaky2(Leaky2Args g) {
  __shared__ h16_t wl[2 * 8192];
  const int zz = blockIdx.z;
  const h16_t* A = zz ? g.A1 : g.A0;
  const h16_t* W = zz ? g.W1 : g.W0;
  const float* bias = zz ? g.b1 : g.b0;
  h16_t* Y = zz ? g.Y1 : g.Y0;
  EPILOGUE_SETUP();
  gemm_run<K>(A, W, m0, o0, wl, acc);
  const int LAYOUT = zz ? L1 : L0;
#pragma unroll
  for (int j = 0; j < 4; ++j)
#pragma unroll
    for (int r = 0; r < 4; ++r) {
      const int o = o0 + j * 16 + l15;
      const int m = m0 + quad * 4 + r;
      float v = acc[j][r] + bias[o];
      v = v > 0.f ? v : 0.2f * v;
      if (LAYOUT == 0) {
        Y[(size_t)m * 512 + o] = (h16_t)v;
      } else {
        const int b = m >> 10, n = m & 1023;
        const int h = o >> 6, d = o & 63;
        if (LAYOUT == 1)
          Y[((size_t)(b * 8 + h) * 1024 + n) * 64 + d] = (h16_t)v;
        else
          Y[((size_t)(b * 8 + h) * 64 + d) * 1024 + n] = (h16_t)v;
      }
    }
}

// ---------------------------------------------------------------------------
// MERGED g0 + qkv (verified Round 6 structure).
// ---------------------------------------------------------------------------
__global__ __launch_bounds__(256) void k_g0_qkv(
    Leaky2Args g, const h16_t* __restrict__ X, const h16_t* __restrict__ Wq,
    h16_t* __restrict__ qb, h16_t* __restrict__ kb, h16_t* __restrict__ vT) {
  __shared__ h16_t wl[2 * 8192];
  const int bid = blockIdx.x;
  const int wv = threadIdx.x >> 6;
  const int lane = threadIdx.x & 63;
  const int l15 = lane & 15;
  const int quad = lane >> 4;
  f32x4 acc[4];
#pragma unroll
  for (int j = 0; j < 4; ++j) acc[j] = f32x4{0.f, 0.f, 0.f, 0.f};

  if (bid < 2048) {
    const int zz = bid >> 10;
    const int m0 = (bid & 127) * 64 + wv * 16;
    const int o0 = ((bid >> 7) & 7) * 64;
    const h16_t* A = zz ? g.A1 : g.A0;
    const h16_t* W = zz ? g.W1 : g.W0;
    const float* bias = zz ? g.b1 : g.b0;
    h16_t* Y = zz ? g.Y1 : g.Y0;
    gemm_run<384>(A, W, m0, o0, wl, acc);
#pragma unroll
    for (int j = 0; j < 4; ++j)
#pragma unroll
      for (int r = 0; r < 4; ++r) {
        const int o = o0 + j * 16 + l15;
        const int m = m0 + quad * 4 + r;
        float v = acc[j][r] + bias[o];
        v = v > 0.f ? v : 0.2f * v;
        Y[(size_t)m * 512 + o] = (h16_t)v;
      }
  } else {
    const int q = bid - 2048;
    const int m0 = (q & 127) * 64 + wv * 16;
    const int o0 = (q >> 7) * 64;
    gemm_run<512>(X, Wq, m0, o0, wl, acc);
#pragma unroll
    for (int j = 0; j < 4; ++j)
#pragma unroll
      for (int r = 0; r < 4; ++r) {
        const int o = o0 + j * 16 + l15;
        const int m = m0 + quad * 4 + r;
        const int b = m >> 10, n = m & 1023;
        const int oo = o & 511, h = oo >> 6, d = oo & 63;
        const size_t bh = (size_t)(b * 8 + h);
        const h16_t v = (h16_t)acc[j][r];
        if (o < 512)
          qb[(bh * 1024 + n) * 64 + d] = v;
        else if (o < 1024)
          kb[(bh * 1024 + n) * 64 + d] = v;
        else
          vT[(bh * 64 + d) * 1024 + n] = v;
      }
  }
}

// nl-MLP GEMM: gelu + combine with attn
__global__ __launch_bounds__(256) void k_gemm_nl(
    const h16_t* __restrict__ A, const h16_t* __restrict__ W,
    const float* __restrict__ bias, const h16_t* __restrict__ attn,
    const float* __restrict__ subr, h16_t* __restrict__ Y) {
  __shared__ h16_t wl[2 * 8192];
  EPILOGUE_SETUP();
  gemm_run<512>(A, W, m0, o0, wl, acc);
#pragma unroll
  for (int j = 0; j < 4; ++j)
#pragma unroll
    for (int r = 0; r < 4; ++r) {
      const int o = o0 + j * 16 + l15;
      const int m = m0 + quad * 4 + r;
      const float v = acc[j][r] + bias[o];
      const float g = 0.5f * v * (1.f + erff(v * 0.70710678118654752f));
      const float res = (float)attn[(size_t)m * 512 + o] - g * subr[o];
      Y[(size_t)m * 512 + o] = (h16_t)res;
    }
}

// final projection (f32 output)
__global__ __launch_bounds__(256) void k_gemm_out(
    const h16_t* __restrict__ A, const h16_t* __restrict__ W,
    const float* __restrict__ bias, float* __restrict__ Y) {
  __shared__ h16_t wl[2 * 8192];
  EPILOGUE_SETUP();
  gemm_run<512>(A, W, m0, o0, wl, acc);
#pragma unroll
  for (int j = 0; j < 4; ++j)
#pragma unroll
    for (int r = 0; r < 4; ++r) {
      const int o = o0 + j * 16 + l15;
      const int m = m0 + quad * 4 + r;
      Y[(size_t)m * 512 + o] = acc[j][r] + bias[o];
    }
}

// ---------------------------------------------------------------------------
// Attention v9: z=2 merged launch (grid x=64 bh for XCD locality, y=8
// q-blocks, z=branch). K double-buffered in LDS (2x8KB, swizzled staging).
// V read DIRECTLY from global/L2 — vT layout means the PV A-fragment is 8
// contiguous halfs at vT[d][mt*64 + s*32 + quad*8], no swizzle, no staging:
// deletes V prefetch loads, LDS stores, and the V-side swizzled LDS reads.
// MFMA l-sum as R7. z=1 additionally accumulates column sum-squares of the
// output into part2 (verified in R8, absmax-identical) - replaces k_cn_rm_p1.
// ---------------------------------------------------------------------------
__global__ __launch_bounds__(256) void k_attn4(
    const h16_t* __restrict__ q,
    const h16_t* __restrict__ k0, const h16_t* __restrict__ v0, h16_t* __restrict__ out0,
    const h16_t* __restrict__ k1, const h16_t* __restrict__ v1, h16_t* __restrict__ out1,
    float* __restrict__ part2) {
  const int wv = threadIdx.x >> 6;
  const int lane = threadIdx.x & 63;
  const int l15 = lane & 15;
  const int quad = lane >> 4;
  const int bh = blockIdx.x, b = bh >> 3, h = bh & 7;
  const h16_t* kb = (blockIdx.z ? k1 : k0) + (size_t)bh * 65536;
  const h16_t* vb = (blockIdx.z ? v1 : v0) + (size_t)bh * 65536;
  h16_t* out = blockIdx.z ? out1 : out0;

  __shared__ h16_t kls[2 * 4096];  // 2 x 8 KB (K only)

  // Q fragments: 2 q-tiles per wave (B-operand)
  const int q0r = blockIdx.y * 128 + wv * 32;
  h16x8 qa[2][2];
#pragma unroll
  for (int t = 0; t < 2; ++t)
#pragma unroll
    for (int s = 0; s < 2; ++s)
      qa[t][s] = *(const h16x8*)(q + ((size_t)bh * 1024 + q0r + t * 16 + l15) * 64 + s * 32 + quad * 8);

  h16x8 ones;
#pragma unroll
  for (int j = 0; j < 8; ++j) ones[j] = (h16_t)1.f;

  // K staging map: thread handles chunks L = tid, tid+256 (16B each).
  int ksrc[2], ldst[2];
#pragma unroll
  for (int i = 0; i < 2; ++i) {
    const int L = threadIdx.x + i * 256;
    const int row = L >> 3, cs = L & 7;
    const int key = ((row & 3) << 1) | ((row >> 3) & 1);
    const int c = cs ^ key;
    ksrc[i] = row * 64 + c * 8;
    ldst[i] = L * 8;
  }

  // K fragment LDS offsets
  int kfo[2][4];
#pragma unroll
  for (int s = 0; s < 2; ++s)
#pragma unroll
    for (int nt = 0; nt < 4; ++nt) {
      const int r = (nt & 1) * 32 + (l15 >> 2) * 8 + (nt >> 1) * 4 + (l15 & 3);
      const int kk = ((r & 3) << 1) | ((r >> 3) & 1);
      kfo[s][nt] = (r * 8 + ((s * 4 + quad) ^ kk)) * 8;
    }

  // V direct-read row base: lane reads vT[d = nt*16+l15][...]
  const h16_t* vrow = vb + (size_t)l15 * 1024 + quad * 8;

  f32x4 oaT[2][4];
#pragma unroll
  for (int t = 0; t < 2; ++t)
#pragma unroll
    for (int j = 0; j < 4; ++j) oaT[t][j] = f32x4{0.f, 0.f, 0.f, 0.f};
  f32x4 lacc[2];
#pragma unroll
  for (int t = 0; t < 2; ++t) lacc[t] = f32x4{0.f, 0.f, 0.f, 0.f};

  // stage K tile 0 into buffer 0
  h16x8 kr[2];
#pragma unroll
  for (int i = 0; i < 2; ++i) kr[i] = *(const h16x8*)(kb + ksrc[i]);
#pragma unroll
  for (int i = 0; i < 2; ++i) *(h16x8*)(kls + ldst[i]) = kr[i];
  __syncthreads();

  for (int mt = 0; mt < 16; ++mt) {
    const int cur = (mt & 1) * 4096;
    if (mt < 15) {  // prefetch next K tile into registers
      const int mm1 = (mt + 1) * 64;
#pragma unroll
      for (int i = 0; i < 2; ++i) kr[i] = *(const h16x8*)(kb + mm1 * 64 + ksrc[i]);
    }

    f32x4 sfT[2][4];
#pragma unroll
    for (int t = 0; t < 2; ++t)
#pragma unroll
      for (int j = 0; j < 4; ++j) sfT[t][j] = f32x4{0.f, 0.f, 0.f, 0.f};
#pragma unroll
    for (int s = 0; s < 2; ++s)
#pragma unroll
      for (int nt = 0; nt < 4; ++nt) {
        h16x8 kf = *(const h16x8*)(kls + cur + kfo[s][nt]);
        sfT[0][nt] = mfma16(kf, qa[0][s], sfT[0][nt]);
        sfT[1][nt] = mfma16(kf, qa[1][s], sfT[1][nt]);
      }
    int pk[2][4][2];
#pragma unroll
    for (int t = 0; t < 2; ++t)
#pragma unroll
      for (int nt = 0; nt < 4; ++nt) {
        const float e0 = __expf(sfT[t][nt][0] * 0.125f);
        const float e1 = __expf(sfT[t][nt][1] * 0.125f);
        const float e2 = __expf(sfT[t][nt][2] * 0.125f);
        const float e3 = __expf(sfT[t][nt][3] * 0.125f);
        pk[t][nt][0] = __builtin_bit_cast(int, __builtin_amdgcn_cvt_pkrtz(e0, e1));
        pk[t][nt][1] = __builtin_bit_cast(int, __builtin_amdgcn_cvt_pkrtz(e2, e3));
      }
#pragma unroll
    for (int s = 0; s < 2; ++s) {
      int4 b0 = {pk[0][s][0], pk[0][s][1], pk[0][s + 2][0], pk[0][s + 2][1]};
      int4 b1 = {pk[1][s][0], pk[1][s][1], pk[1][s + 2][0], pk[1][s + 2][1]};
      h16x8 bf0 = __builtin_bit_cast(h16x8, b0);
      h16x8 bf1 = __builtin_bit_cast(h16x8, b1);
      lacc[0] = mfma16(ones, bf0, lacc[0]);
      lacc[1] = mfma16(ones, bf1, lacc[1]);
#pragma unroll
      for (int nt = 0; nt < 4; ++nt) {
        // V directly from global: keys s*32+quad*8+j of tile mt, row d
        h16x8 vf = *(const h16x8*)(vrow + (size_t)nt * 16384 + mt * 64 + s * 32);
        oaT[0][nt] = mfma16(vf, bf0, oaT[0][nt]);
        oaT[1][nt] = mfma16(vf, bf1, oaT[1][nt]);
      }
    }

    if (mt < 15) {  // store prefetched K into the OTHER buffer
      const int nxt = ((mt + 1) & 1) * 4096;
#pragma unroll
      for (int i = 0; i < 2; ++i) *(h16x8*)(kls + nxt + ldst[i]) = kr[i];
    }
    __syncthreads();
  }

  const bool SQ = blockIdx.z != 0;
  float sq[4][4];
  if (SQ) {
#pragma unroll
    for (int nt = 0; nt < 4; ++nt)
#pragma unroll
      for (int r = 0; r < 4; ++r) sq[nt][r] = 0.f;
  }
#pragma unroll
  for (int t = 0; t < 2; ++t) {
    const float iv = 1.f / lacc[t][0];
    h16_t* obase = out + ((size_t)b * 1024 + q0r + t * 16 + l15) * 512 + h * 64 + quad * 4;
#pragma unroll
    for (int nt = 0; nt < 4; ++nt) {
      h16x4 o;
#pragma unroll
      for (int r = 0; r < 4; ++r) {
        const float v = oaT[t][nt][r] * iv;
        o[r] = (h16_t)v;
        if (SQ) sq[nt][r] += v * v;
      }
      *(h16x4*)(obase + nt * 16) = o;
    }
  }
  if (SQ) {
#pragma unroll
    for (int nt = 0; nt < 4; ++nt)
#pragma unroll
      for (int r = 0; r < 4; ++r) {
        float s = sq[nt][r];
        s += __shfl_xor(s, 1);
        s += __shfl_xor(s, 2);
        s += __shfl_xor(s, 4);
        s += __shfl_xor(s, 8);
        if (l15 == 0)
          atomicAdd(&part2[b * 512 + h * 64 + nt * 16 + quad * 4 + r], s);
      }
  }
}

// ---------------------------------------------------------------------------
// Norm helpers
// ---------------------------------------------------------------------------
__global__ __launch_bounds__(384) void k_cn_ck_p2(const float* __restrict__ part,
                                                  float* __restrict__ inv,
                                                  float* __restrict__ part2) {
  const int b = blockIdx.x, z = blockIdx.y, f = threadIdx.x;
  if (z == 0) {  // zero part2 for this iteration's attn-ctx accumulation
    for (int t = f; t < 512; t += 384) part2[b * 512 + t] = 0.f;
  }
  float s = 0.f;
#pragma unroll 8
  for (int ch = 0; ch < 64; ++ch)
    s += part[(size_t)z * 196608 + (size_t)(b * 64 + ch) * 384 + f];
  inv[z * 3072 + b * 384 + f] = 1.f / fmaxf(sqrtf(s), 1e-12f);
}

__global__ __launch_bounds__(384) void k_norm_ck(const float* __restrict__ c0,
                                                 const float* __restrict__ c1,
                                                 const float* __restrict__ inv,
                                                 h16_t* __restrict__ y0,
                                                 h16_t* __restrict__ y1) {
  const int bn = blockIdx.x, z = blockIdx.y, f = threadIdx.x;
  const float* c = z ? c1 : c0;
  h16_t* out = z ? y1 : y0;
  const int b = bn >> 10, n = bn & 1023;
  const int h = f >> 6, d = f & 63;
  out[(size_t)bn * 384 + f] =
      (h16_t)(c[((size_t)(b * 6 + h) * 1024 + n) * 64 + d] * inv[z * 3072 + b * 384 + f]);
}

__global__ __launch_bounds__(512) void k_rm_p2b(const float* __restrict__ part2,
                                                float* __restrict__ inv) {
  const int b = blockIdx.x, f = threadIdx.x;
  inv[b * 512 + f] = 1.f / fmaxf(sqrtf(part2[b * 512 + f]), 1e-12f);
}

__global__ __launch_bounds__(512) void k_norm_rm(const h16_t* __restrict__ a,
                                                 const float* __restrict__ inv,
                                                 h16_t* __restrict__ out) {
  const int bn = blockIdx.x, f = threadIdx.x;
  const int b = bn >> 10;
  out[(size_t)bn * 512 + f] = (h16_t)((float)a[(size_t)bn * 512 + f] * inv[b * 512 + f]);
}

// ---------------------------------------------------------------------------
// Schedule v15 (R7 structure + V-direct attn + sq-fold):
//  0. MERGED: cvt {x->S5, weights->WB} || colnorm p1 -> part
//  1. p2 -> inv1 (+zero part2); norm (ck->T0, cv->S0)
//  2. MERGED: g0 {T0->T1, S0->S1} || qkv {S5 -> Q:S2, K:S3, vT:S4}
//  3. g1: T1->T0, S1->S0
//  4. g2: T0->T1 bhnd (ckh), S0->S1 bhdn (cvT)
//  5. attn z=2: z0 (S2,S3,S4)->ATTN(T0); z1 (S2,T1,S1)->S5 + sq->part2
//  6. rm_p2b: part2 -> inv1; norm_rm: S5 -> S0
//  7. nl GEMM: S0 + ATTN(T0) -> S1
//  8. out GEMM: S1 -> d_out (f32)
// ---------------------------------------------------------------------------
extern "C" void kernel_launch(void* const* d_in, const int* in_sizes, int n_in,
                              void* d_out, int out_size, void* d_ws, size_t ws_size,
                              hipStream_t stream) {
  (void)in_sizes; (void)n_in; (void)out_size; (void)ws_size;
  const float* x     = (const float*)d_in[0];
  const float* ck    = (const float*)d_in[1];
  const float* cv    = (const float*)d_in[2];
  const float* w_qkv = (const float*)d_in[3];
  const float* w_out = (const float*)d_in[4];
  const float* b_out = (const float*)d_in[5];
  const float* ckw0  = (const float*)d_in[6];
  const float* ckb0  = (const float*)d_in[7];
  const float* ckw1  = (const float*)d_in[8];
  const float* ckb1  = (const float*)d_in[9];
  const float* ckw2  = (const float*)d_in[10];
  const float* ckb2  = (const float*)d_in[11];
  const float* cvw0  = (const float*)d_in[12];
  const float* cvb0  = (const float*)d_in[13];
  const float* cvw1  = (const float*)d_in[14];
  const float* cvb1  = (const float*)d_in[15];
  const float* cvw2  = (const float*)d_in[16];
  const float* cvb2  = (const float*)d_in[17];
  const float* nl_w  = (const float*)d_in[18];
  const float* nl_b  = (const float*)d_in[19];
  const float* subr  = (const float*)d_in[20];

  const size_t MB = 1024 * 1024;
  char* p = (char*)d_ws;
  float* inv1 = (float*)p;                          // 24 KB used of 64 KB
  float* part = (float*)(p + 64 * 1024);            // 1.5 MB (colnorm partials)
  float* part2 = (float*)(p + 1600 * 1024);         // 16 KB (rm partials)
  h16_t* S0 = (h16_t*)(p + 2 * MB + 0 * 8 * MB);
  h16_t* S1 = (h16_t*)(p + 2 * MB + 1 * 8 * MB);
  h16_t* S2 = (h16_t*)(p + 2 * MB + 2 * 8 * MB);  // Q
  h16_t* S3 = (h16_t*)(p + 2 * MB + 3 * 8 * MB);  // K_self
  h16_t* S4 = (h16_t*)(p + 2 * MB + 4 * 8 * MB);  // vT_self
  h16_t* S5 = (h16_t*)(p + 2 * MB + 5 * 8 * MB);  // XB, later outc
  h16_t* WBASE = (h16_t*)(p + 50 * MB);
  h16_t* w_qkvb = WBASE;
  h16_t* w_outb = w_qkvb + 786432;
  h16_t* ckw0b  = w_outb + 262144;
  h16_t* ckw1b  = ckw0b + 196608;
  h16_t* ckw2b  = ckw1b + 262144;
  h16_t* cvw0b  = ckw2b + 262144;
  h16_t* cvw1b  = cvw0b + 196608;
  h16_t* cvw2b  = cvw1b + 262144;
  h16_t* nl_wb  = cvw2b + 262144;
  h16_t* T0   = (h16_t*)d_out;            // d_out lower 8MB (scratch, ATTN)
  h16_t* T1   = (h16_t*)d_out + 4194304;  // d_out upper 8MB (scratch, ckh)
  h16_t* XB   = S5;
  h16_t* ATTN = T0;

  const dim3 blk(256);
  // 0. MERGED cvt || colnorm p1
  {
    CvtArgs a;
    const float* srcs[10] = {x, w_qkv, w_out, ckw0, ckw1, ckw2, cvw0, cvw1, cvw2, nl_w};
    h16_t* dsts[10] = {XB, w_qkvb, w_outb, ckw0b, ckw1b, ckw2b, cvw0b, cvw1b, cvw2b, nl_wb};
    const int ns[10] = {4194304, 786432, 262144, 196608, 262144, 262144, 196608, 262144, 262144, 262144};
    int cum = 0;
    for (int i = 0; i < 10; ++i) {
      a.src[i] = srcs[i]; a.dst[i] = dsts[i]; a.start4[i] = cum; cum += ns[i] / 4;
    }
    a.total4 = cum;
    a.nblk_cvt = (cum + 383) / 384;
    a.c0 = ck; a.c1 = cv; a.part = part;
    k_cvt_p1<<<a.nblk_cvt + 1024, 384, 0, stream>>>(a);
  }

  // 1. colnorm p2 (+zero part2) + apply
  k_cn_ck_p2<<<dim3(8, 2), 384, 0, stream>>>(part, inv1, part2);
  k_norm_ck<<<dim3(8192, 2), 384, 0, stream>>>(ck, cv, inv1, T0, S0);

  // 2. MERGED g0 || qkv
  {
    Leaky2Args g = {T0, ckw0b, ckb0, T1, S0, cvw0b, cvb0, S1};
    k_g0_qkv<<<5120, blk, 0, stream>>>(g, XB, w_qkvb, S2, S3, S4);
  }

  // 3. g1
  {
    Leaky2Args g = {T1, ckw1b, ckb1, T0, S1, cvw1b, cvb1, S0};
    k_gemm_leaky2<512, 0, 0><<<dim3(128, 8, 2), blk, 0, stream>>>(g);
  }

  // 4. g2: ck -> ckh (T1, bhnd), cv -> cvT (S1, bhdn)
  {
    Leaky2Args g = {T0, ckw2b, ckb2, T1, S0, cvw2b, cvb2, S1};
    k_gemm_leaky2<512, 1, 2><<<dim3(128, 8, 2), blk, 0, stream>>>(g);
  }

  // 5. merged attention z=2 (V direct from global); z=1 accumulates part2
  k_attn4<<<dim3(64, 8, 2), blk, 0, stream>>>(S2, S3, S4, ATTN, T1, S1, S5, part2);

  // 6. rm inverse norms + apply: S5 -> S0
  k_rm_p2b<<<8, 512, 0, stream>>>(part2, inv1);
  k_norm_rm<<<8192, 512, 0, stream>>>(S5, inv1, S0);
  // 7. GEMM+GELU+combine with attn -> S1
  k_gemm_nl<<<dim3(128, 8), blk, 0, stream>>>(S0, nl_wb, nl_b, ATTN, subr, S1);
  // 8. final projection -> d_out (f32)
  k_gemm_out<<<dim3(128, 8), blk, 0, stream>>>(S1, w_outb, b_out, (float*)d_out);
}

// Round 10
// 342.765 us; speedup vs baseline: 1.1416x; 1.1416x over previous
//
#include <hip/hip_runtime.h>
#include <hip/hip_fp16.h>
#include <math.h>

typedef _Float16 h16_t;
typedef __attribute__((ext_vector_type(4))) _Float16 h16x4;
typedef __attribute__((ext_vector_type(8))) _Float16 h16x8;
typedef __attribute__((ext_vector_type(4))) float f32x4;

static_assert(sizeof(h16_t) == 2, "f16 size");

__device__ __forceinline__ f32x4 mfma16(h16x8 a, h16x8 b, f32x4 c) {
  return __builtin_amdgcn_mfma_f32_16x16x32_f16(a, b, c, 0, 0, 0);
}

// ---------------------------------------------------------------------------
// MERGED: fused f32->f16 conversion (10 segments) || ck/cv colnorm phase 1.
// ---------------------------------------------------------------------------
struct CvtArgs {
  const float* src[10];
  h16_t* dst[10];
  int start4[10];
  int total4;
  int nblk_cvt;
  const float* c0;
  const float* c1;
  float* part;
};

__global__ __launch_bounds__(384) void k_cvt_p1(CvtArgs a) {
  const int bid = blockIdx.x;
  if (bid < a.nblk_cvt) {  // --- cvt path ---
    const int i4 = bid * 384 + threadIdx.x;
    if (i4 >= a.total4) return;
    int seg = 0;
#pragma unroll
    for (int t = 1; t < 10; ++t) seg += (i4 >= a.start4[t]) ? 1 : 0;
    const int off = (i4 - a.start4[seg]) * 4;
    const float4 v = *(const float4*)(a.src[seg] + off);
    h16x4 o;
    o[0] = (h16_t)v.x; o[1] = (h16_t)v.y; o[2] = (h16_t)v.z; o[3] = (h16_t)v.w;
    *(h16x4*)(a.dst[seg] + off) = o;
  } else {  // --- cn_ck_p1 path ---
    const int rid = bid - a.nblk_cvt;
    const int b = rid & 7, ch = (rid >> 3) & 63, z = rid >> 9;
    const int f = threadIdx.x;
    const float* c = z ? a.c1 : a.c0;
    const int h = f >> 6, d = f & 63;
    const float* p = c + ((size_t)(b * 6 + h) * 1024 + ch * 16) * 64 + d;
    float s = 0.f;
#pragma unroll
    for (int n = 0; n < 16; ++n) {
      const float v = p[(size_t)n * 64];
      s += v * v;
    }
    a.part[(size_t)z * 196608 + (size_t)(b * 64 + ch) * 384 + f] = s;
  }
}

// ---------------------------------------------------------------------------
// GEMM core: W staged through DOUBLE-BUFFERED 128-col segments (2x16KB LDS).
// ---------------------------------------------------------------------------
template <int K>
__device__ __forceinline__ void gemm_run(const h16_t* __restrict__ A,
                                         const h16_t* __restrict__ W,
                                         int m0, int o0, h16_t* wl, f32x4* acc) {
  constexpr int NS = K / 128;
  const int lane = threadIdx.x & 63;
  const int l15 = lane & 15;
  const int quad = lane >> 4;
  int sr[4], sc[4], sd[4];
#pragma unroll
  for (int i = 0; i < 4; ++i) {
    const int id = threadIdx.x + i * 256;
    const int row = id >> 4, c = id & 15;
    sr[i] = row;
    sc[i] = c * 8;
    sd[i] = (row * 16 + (c ^ (row & 7))) * 8;
  }
  h16x8 wr[4];
#pragma unroll
  for (int i = 0; i < 4; ++i)
    wr[i] = *(const h16x8*)(W + (size_t)(o0 + sr[i]) * K + sc[i]);
#pragma unroll
  for (int i = 0; i < 4; ++i) *(h16x8*)(wl + sd[i]) = wr[i];
  __syncthreads();
#pragma unroll
  for (int sg = 0; sg < NS; ++sg) {
    if (sg + 1 < NS) {
#pragma unroll
      for (int i = 0; i < 4; ++i)
        wr[i] = *(const h16x8*)(W + (size_t)(o0 + sr[i]) * K + (sg + 1) * 128 + sc[i]);
    }
    const h16_t* ap = A + (size_t)(m0 + l15) * K + sg * 128 + quad * 8;
    const h16_t* wp = wl + (sg & 1) * 8192;
#pragma unroll
    for (int ks = 0; ks < 4; ++ks) {
      h16x8 af = *(const h16x8*)(ap + ks * 32);
#pragma unroll
      for (int j = 0; j < 4; ++j) {
        h16x8 wf = *(const h16x8*)(
            wp + (size_t)((j * 16 + l15) * 16 + ((ks * 4 + quad) ^ (l15 & 7))) * 8);
        acc[j] = mfma16(af, wf, acc[j]);
      }
    }
    if (sg + 1 < NS) {
      h16_t* wn = wl + ((sg + 1) & 1) * 8192;
#pragma unroll
      for (int i = 0; i < 4; ++i) *(h16x8*)(wn + sd[i]) = wr[i];
    }
    __syncthreads();
  }
}

#define EPILOGUE_SETUP()                            \
  const int wv = threadIdx.x >> 6;                  \
  const int lane = threadIdx.x & 63;                \
  const int l15 = lane & 15;                        \
  const int quad = lane >> 4;                       \
  const int m0 = blockIdx.x * 64 + wv * 16;         \
  const int o0 = blockIdx.y * 64;                   \
  f32x4 acc[4];                                     \
  for (int j = 0; j < 4; ++j) acc[j] = f32x4{0.f, 0.f, 0.f, 0.f};

struct Leaky2Args {
  const h16_t* A0; const h16_t* W0; const float* b0; h16_t* Y0;
  const h16_t* A1; const h16_t* W1; const float* b1; h16_t* Y1;
};

// LeakyReLU GEMM, z-merged. LAYOUT: 0 row-major; 1 (b,h,n,d); 2 (b,h,d,n)
template <int K, int L0, int L1>
__global__ __launch_bounds__(256) void k_gemm_leaky2(Leaky2Args g) {
  __shared__ h16_t wl[2 * 8192];
  const int zz = blockIdx.z;
  const h16_t* A = zz ? g.A1 : g.A0;
  const h16_t* W = zz ? g.W1 : g.W0;
  const float* bias = zz ? g.b1 : g.b0;
  h16_t* Y = zz ? g.Y1 : g.Y0;
  EPILOGUE_SETUP();
  gemm_run<K>(A, W, m0, o0, wl, acc);
  const int LAYOUT = zz ? L1 : L0;
#pragma unroll
  for (int j = 0; j < 4; ++j)
#pragma unroll
    for (int r = 0; r < 4; ++r) {
      const int o = o0 + j * 16 + l15;
      const int m = m0 + quad * 4 + r;
      float v = acc[j][r] + bias[o];
      v = v > 0.f ? v : 0.2f * v;
      if (LAYOUT == 0) {
        Y[(size_t)m * 512 + o] = (h16_t)v;
      } else {
        const int b = m >> 10, n = m & 1023;
        const int h = o >> 6, d = o & 63;
        if (LAYOUT == 1)
          Y[((size_t)(b * 8 + h) * 1024 + n) * 64 + d] = (h16_t)v;
        else
          Y[((size_t)(b * 8 + h) * 64 + d) * 1024 + n] = (h16_t)v;
      }
    }
}

// ---------------------------------------------------------------------------
// MERGED g0 + qkv (verified Round 6 structure).
// ---------------------------------------------------------------------------
__global__ __launch_bounds__(256) void k_g0_qkv(
    Leaky2Args g, const h16_t* __restrict__ X, const h16_t* __restrict__ Wq,
    h16_t* __restrict__ qb, h16_t* __restrict__ kb, h16_t* __restrict__ vT) {
  __shared__ h16_t wl[2 * 8192];
  const int bid = blockIdx.x;
  const int wv = threadIdx.x >> 6;
  const int lane = threadIdx.x & 63;
  const int l15 = lane & 15;
  const int quad = lane >> 4;
  f32x4 acc[4];
#pragma unroll
  for (int j = 0; j < 4; ++j) acc[j] = f32x4{0.f, 0.f, 0.f, 0.f};

  if (bid < 2048) {
    const int zz = bid >> 10;
    const int m0 = (bid & 127) * 64 + wv * 16;
    const int o0 = ((bid >> 7) & 7) * 64;
    const h16_t* A = zz ? g.A1 : g.A0;
    const h16_t* W = zz ? g.W1 : g.W0;
    const float* bias = zz ? g.b1 : g.b0;
    h16_t* Y = zz ? g.Y1 : g.Y0;
    gemm_run<384>(A, W, m0, o0, wl, acc);
#pragma unroll
    for (int j = 0; j < 4; ++j)
#pragma unroll
      for (int r = 0; r < 4; ++r) {
        const int o = o0 + j * 16 + l15;
        const int m = m0 + quad * 4 + r;
        float v = acc[j][r] + bias[o];
        v = v > 0.f ? v : 0.2f * v;
        Y[(size_t)m * 512 + o] = (h16_t)v;
      }
  } else {
    const int q = bid - 2048;
    const int m0 = (q & 127) * 64 + wv * 16;
    const int o0 = (q >> 7) * 64;
    gemm_run<512>(X, Wq, m0, o0, wl, acc);
#pragma unroll
    for (int j = 0; j < 4; ++j)
#pragma unroll
      for (int r = 0; r < 4; ++r) {
        const int o = o0 + j * 16 + l15;
        const int m = m0 + quad * 4 + r;
        const int b = m >> 10, n = m & 1023;
        const int oo = o & 511, h = oo >> 6, d = oo & 63;
        const size_t bh = (size_t)(b * 8 + h);
        const h16_t v = (h16_t)acc[j][r];
        if (o < 512)
          qb[(bh * 1024 + n) * 64 + d] = v;
        else if (o < 1024)
          kb[(bh * 1024 + n) * 64 + d] = v;
        else
          vT[(bh * 64 + d) * 1024 + n] = v;
      }
  }
}

// nl-MLP GEMM: gelu + combine with attn
__global__ __launch_bounds__(256) void k_gemm_nl(
    const h16_t* __restrict__ A, const h16_t* __restrict__ W,
    const float* __restrict__ bias, const h16_t* __restrict__ attn,
    const float* __restrict__ subr, h16_t* __restrict__ Y) {
  __shared__ h16_t wl[2 * 8192];
  EPILOGUE_SETUP();
  gemm_run<512>(A, W, m0, o0, wl, acc);
#pragma unroll
  for (int j = 0; j < 4; ++j)
#pragma unroll
    for (int r = 0; r < 4; ++r) {
      const int o = o0 + j * 16 + l15;
      const int m = m0 + quad * 4 + r;
      const float v = acc[j][r] + bias[o];
      const float g = 0.5f * v * (1.f + erff(v * 0.70710678118654752f));
      const float res = (float)attn[(size_t)m * 512 + o] - g * subr[o];
      Y[(size_t)m * 512 + o] = (h16_t)res;
    }
}

// final projection (f32 output)
__global__ __launch_bounds__(256) void k_gemm_out(
    const h16_t* __restrict__ A, const h16_t* __restrict__ W,
    const float* __restrict__ bias, float* __restrict__ Y) {
  __shared__ h16_t wl[2 * 8192];
  EPILOGUE_SETUP();
  gemm_run<512>(A, W, m0, o0, wl, acc);
#pragma unroll
  for (int j = 0; j < 4; ++j)
#pragma unroll
    for (int r = 0; r < 4; ++r) {
      const int o = o0 + j * 16 + l15;
      const int m = m0 + quad * 4 + r;
      Y[(size_t)m * 512 + o] = acc[j][r] + bias[o];
    }
}

// ---------------------------------------------------------------------------
// Attention v10 = R7's verified kernel (z=2, bh-major grid for XCD locality,
// K AND V double-buffered in LDS, MFMA l-sum) + sq-fold on z=1 (verified in
// R8/R9: absmax-identical): accumulates column sum-squares of outc into
// part2, replacing the k_cn_rm_p1 pass.
// ---------------------------------------------------------------------------
__global__ __launch_bounds__(256) void k_attn4(
    const h16_t* __restrict__ q,
    const h16_t* __restrict__ k0, const h16_t* __restrict__ v0, h16_t* __restrict__ out0,
    const h16_t* __restrict__ k1, const h16_t* __restrict__ v1, h16_t* __restrict__ out1,
    float* __restrict__ part2) {
  const int wv = threadIdx.x >> 6;
  const int lane = threadIdx.x & 63;
  const int l15 = lane & 15;
  const int quad = lane >> 4;
  const int bh = blockIdx.x, b = bh >> 3, h = bh & 7;
  const h16_t* kb = (blockIdx.z ? k1 : k0) + (size_t)bh * 65536;
  const h16_t* vb = (blockIdx.z ? v1 : v0) + (size_t)bh * 65536;
  h16_t* out = blockIdx.z ? out1 : out0;

  __shared__ h16_t kls[2 * 4096];  // 2 x 8 KB
  __shared__ h16_t vls[2 * 4096];  // 2 x 8 KB

  const int q0r = blockIdx.y * 128 + wv * 32;
  h16x8 qa[2][2];
#pragma unroll
  for (int t = 0; t < 2; ++t)
#pragma unroll
    for (int s = 0; s < 2; ++s)
      qa[t][s] = *(const h16x8*)(q + ((size_t)bh * 1024 + q0r + t * 16 + l15) * 64 + s * 32 + quad * 8);

  h16x8 ones;
#pragma unroll
  for (int j = 0; j < 8; ++j) ones[j] = (h16_t)1.f;

  int ksrc[2], vsrc[2], ldst[2];
#pragma unroll
  for (int i = 0; i < 2; ++i) {
    const int L = threadIdx.x + i * 256;
    const int row = L >> 3, cs = L & 7;
    const int key = ((row & 3) << 1) | ((row >> 3) & 1);
    const int c = cs ^ key;
    ksrc[i] = row * 64 + c * 8;
    vsrc[i] = row * 1024 + c * 8;
    ldst[i] = L * 8;
  }

  int kfo[2][4], vfo[2][4];
#pragma unroll
  for (int s = 0; s < 2; ++s)
#pragma unroll
    for (int nt = 0; nt < 4; ++nt) {
      const int r = (nt & 1) * 32 + (l15 >> 2) * 8 + (nt >> 1) * 4 + (l15 & 3);
      const int kk = ((r & 3) << 1) | ((r >> 3) & 1);
      kfo[s][nt] = (r * 8 + ((s * 4 + quad) ^ kk)) * 8;
      const int d = nt * 16 + l15;
      const int kd = ((d & 3) << 1) | ((d >> 3) & 1);
      vfo[s][nt] = (d * 8 + ((s * 4 + quad) ^ kd)) * 8;
    }

  f32x4 oaT[2][4];
#pragma unroll
  for (int t = 0; t < 2; ++t)
#pragma unroll
    for (int j = 0; j < 4; ++j) oaT[t][j] = f32x4{0.f, 0.f, 0.f, 0.f};
  f32x4 lacc[2];
#pragma unroll
  for (int t = 0; t < 2; ++t) lacc[t] = f32x4{0.f, 0.f, 0.f, 0.f};

  h16x8 kr[2], vr[2];
#pragma unroll
  for (int i = 0; i < 2; ++i) {
    kr[i] = *(const h16x8*)(kb + ksrc[i]);
    vr[i] = *(const h16x8*)(vb + vsrc[i]);
  }
#pragma unroll
  for (int i = 0; i < 2; ++i) {
    *(h16x8*)(kls + ldst[i]) = kr[i];
    *(h16x8*)(vls + ldst[i]) = vr[i];
  }
  __syncthreads();

  for (int mt = 0; mt < 16; ++mt) {
    const int cur = (mt & 1) * 4096;
    if (mt < 15) {
      const int mm1 = (mt + 1) * 64;
#pragma unroll
      for (int i = 0; i < 2; ++i) {
        kr[i] = *(const h16x8*)(kb + mm1 * 64 + ksrc[i]);
        vr[i] = *(const h16x8*)(vb + mm1 + vsrc[i]);
      }
    }

    f32x4 sfT[2][4];
#pragma unroll
    for (int t = 0; t < 2; ++t)
#pragma unroll
      for (int j = 0; j < 4; ++j) sfT[t][j] = f32x4{0.f, 0.f, 0.f, 0.f};
#pragma unroll
    for (int s = 0; s < 2; ++s)
#pragma unroll
      for (int nt = 0; nt < 4; ++nt) {
        h16x8 kf = *(const h16x8*)(kls + cur + kfo[s][nt]);
        sfT[0][nt] = mfma16(kf, qa[0][s], sfT[0][nt]);
        sfT[1][nt] = mfma16(kf, qa[1][s], sfT[1][nt]);
      }
    int pk[2][4][2];
#pragma unroll
    for (int t = 0; t < 2; ++t)
#pragma unroll
      for (int nt = 0; nt < 4; ++nt) {
        const float e0 = __expf(sfT[t][nt][0] * 0.125f);
        const float e1 = __expf(sfT[t][nt][1] * 0.125f);
        const float e2 = __expf(sfT[t][nt][2] * 0.125f);
        const float e3 = __expf(sfT[t][nt][3] * 0.125f);
        pk[t][nt][0] = __builtin_bit_cast(int, __builtin_amdgcn_cvt_pkrtz(e0, e1));
        pk[t][nt][1] = __builtin_bit_cast(int, __builtin_amdgcn_cvt_pkrtz(e2, e3));
      }
#pragma unroll
    for (int s = 0; s < 2; ++s) {
      int4 b0 = {pk[0][s][0], pk[0][s][1], pk[0][s + 2][0], pk[0][s + 2][1]};
      int4 b1 = {pk[1][s][0], pk[1][s][1], pk[1][s + 2][0], pk[1][s + 2][1]};
      h16x8 bf0 = __builtin_bit_cast(h16x8, b0);
      h16x8 bf1 = __builtin_bit_cast(h16x8, b1);
      lacc[0] = mfma16(ones, bf0, lacc[0]);
      lacc[1] = mfma16(ones, bf1, lacc[1]);
#pragma unroll
      for (int nt = 0; nt < 4; ++nt) {
        h16x8 vf = *(const h16x8*)(vls + cur + vfo[s][nt]);
        oaT[0][nt] = mfma16(vf, bf0, oaT[0][nt]);
        oaT[1][nt] = mfma16(vf, bf1, oaT[1][nt]);
      }
    }

    if (mt < 15) {
      const int nxt = ((mt + 1) & 1) * 4096;
#pragma unroll
      for (int i = 0; i < 2; ++i) {
        *(h16x8*)(kls + nxt + ldst[i]) = kr[i];
        *(h16x8*)(vls + nxt + ldst[i]) = vr[i];
      }
    }
    __syncthreads();
  }

  const bool SQ = blockIdx.z != 0;
  float sq[4][4];
  if (SQ) {
#pragma unroll
    for (int nt = 0; nt < 4; ++nt)
#pragma unroll
      for (int r = 0; r < 4; ++r) sq[nt][r] = 0.f;
  }
#pragma unroll
  for (int t = 0; t < 2; ++t) {
    const float iv = 1.f / lacc[t][0];
    h16_t* obase = out + ((size_t)b * 1024 + q0r + t * 16 + l15) * 512 + h * 64 + quad * 4;
#pragma unroll
    for (int nt = 0; nt < 4; ++nt) {
      h16x4 o;
#pragma unroll
      for (int r = 0; r < 4; ++r) {
        const float v = oaT[t][nt][r] * iv;
        o[r] = (h16_t)v;
        if (SQ) sq[nt][r] += v * v;
      }
      *(h16x4*)(obase + nt * 16) = o;
    }
  }
  if (SQ) {
#pragma unroll
    for (int nt = 0; nt < 4; ++nt)
#pragma unroll
      for (int r = 0; r < 4; ++r) {
        float s = sq[nt][r];
        s += __shfl_xor(s, 1);
        s += __shfl_xor(s, 2);
        s += __shfl_xor(s, 4);
        s += __shfl_xor(s, 8);
        if (l15 == 0)
          atomicAdd(&part2[b * 512 + h * 64 + nt * 16 + quad * 4 + r], s);
      }
  }
}

// ---------------------------------------------------------------------------
// Norm helpers
// ---------------------------------------------------------------------------
__global__ __launch_bounds__(384) void k_cn_ck_p2(const float* __restrict__ part,
                                                  float* __restrict__ inv,
                                                  float* __restrict__ part2) {
  const int b = blockIdx.x, z = blockIdx.y, f = threadIdx.x;
  if (z == 0) {  // zero part2 for this iteration's attn-ctx accumulation
    for (int t = f; t < 512; t += 384) part2[b * 512 + t] = 0.f;
  }
  float s = 0.f;
#pragma unroll 8
  for (int ch = 0; ch < 64; ++ch)
    s += part[(size_t)z * 196608 + (size_t)(b * 64 + ch) * 384 + f];
  inv[z * 3072 + b * 384 + f] = 1.f / fmaxf(sqrtf(s), 1e-12f);
}

__global__ __launch_bounds__(384) void k_norm_ck(const float* __restrict__ c0,
                                                 const float* __restrict__ c1,
                                                 const float* __restrict__ inv,
                                                 h16_t* __restrict__ y0,
                                                 h16_t* __restrict__ y1) {
  const int bn = blockIdx.x, z = blockIdx.y, f = threadIdx.x;
  const float* c = z ? c1 : c0;
  h16_t* out = z ? y1 : y0;
  const int b = bn >> 10, n = bn & 1023;
  const int h = f >> 6, d = f & 63;
  out[(size_t)bn * 384 + f] =
      (h16_t)(c[((size_t)(b * 6 + h) * 1024 + n) * 64 + d] * inv[z * 3072 + b * 384 + f]);
}

__global__ __launch_bounds__(512) void k_rm_p2b(const float* __restrict__ part2,
                                                float* __restrict__ inv) {
  const int b = blockIdx.x, f = threadIdx.x;
  inv[b * 512 + f] = 1.f / fmaxf(sqrtf(part2[b * 512 + f]), 1e-12f);
}

__global__ __launch_bounds__(512) void k_norm_rm(const h16_t* __restrict__ a,
                                                 const float* __restrict__ inv,
                                                 h16_t* __restrict__ out) {
  const int bn = blockIdx.x, f = threadIdx.x;
  const int b = bn >> 10;
  out[(size_t)bn * 512 + f] = (h16_t)((float)a[(size_t)bn * 512 + f] * inv[b * 512 + f]);
}

// ---------------------------------------------------------------------------
// Schedule v16 (= R7's verified v13 + sq-fold deleting k_cn_rm_p1):
//  0. MERGED: cvt {x->S5, weights->WB} || colnorm p1 -> part
//  1. p2 -> inv1 (+zero part2); norm (ck->T0, cv->S0)
//  2. MERGED: g0 {T0->T1, S0->S1} || qkv {S5 -> Q:S2, K:S3, vT:S4}
//  3. g1: T1->T0, S1->S0
//  4. g2: T0->T1 bhnd (ckh), S0->S1 bhdn (cvT)
//  5. attn z=2 (bh-major): z0 (S2,S3,S4)->ATTN(T0); z1 (S2,T1,S1)->S5 + sq->part2
//  6. rm_p2b: part2 -> inv1; norm_rm: S5 -> S0
//  7. nl GEMM: S0 + ATTN(T0) -> S1
//  8. out GEMM: S1 -> d_out (f32)
// ---------------------------------------------------------------------------
extern "C" void kernel_launch(void* const* d_in, const int* in_sizes, int n_in,
                              void* d_out, int out_size, void* d_ws, size_t ws_size,
                              hipStream_t stream) {
  (void)in_sizes; (void)n_in; (void)out_size; (void)ws_size;
  const float* x     = (const float*)d_in[0];
  const float* ck    = (const float*)d_in[1];
  const float* cv    = (const float*)d_in[2];
  const float* w_qkv = (const float*)d_in[3];
  const float* w_out = (const float*)d_in[4];
  const float* b_out = (const float*)d_in[5];
  const float* ckw0  = (const float*)d_in[6];
  const float* ckb0  = (const float*)d_in[7];
  const float* ckw1  = (const float*)d_in[8];
  const float* ckb1  = (const float*)d_in[9];
  const float* ckw2  = (const float*)d_in[10];
  const float* ckb2  = (const float*)d_in[11];
  const float* cvw0  = (const float*)d_in[12];
  const float* cvb0  = (const float*)d_in[13];
  const float* cvw1  = (const float*)d_in[14];
  const float* cvb1  = (const float*)d_in[15];
  const float* cvw2  = (const float*)d_in[16];
  const float* cvb2  = (const float*)d_in[17];
  const float* nl_w  = (const float*)d_in[18];
  const float* nl_b  = (const float*)d_in[19];
  const float* subr  = (const float*)d_in[20];

  const size_t MB = 1024 * 1024;
  char* p = (char*)d_ws;
  float* inv1 = (float*)p;                          // 24 KB used of 64 KB
  float* part = (float*)(p + 64 * 1024);            // 1.5 MB (colnorm partials)
  float* part2 = (float*)(p + 1600 * 1024);         // 16 KB (rm partials)
  h16_t* S0 = (h16_t*)(p + 2 * MB + 0 * 8 * MB);
  h16_t* S1 = (h16_t*)(p + 2 * MB + 1 * 8 * MB);
  h16_t* S2 = (h16_t*)(p + 2 * MB + 2 * 8 * MB);  // Q
  h16_t* S3 = (h16_t*)(p + 2 * MB + 3 * 8 * MB);  // K_self
  h16_t* S4 = (h16_t*)(p + 2 * MB + 4 * 8 * MB);  // vT_self
  h16_t* S5 = (h16_t*)(p + 2 * MB + 5 * 8 * MB);  // XB, later outc
  h16_t* WBASE = (h16_t*)(p + 50 * MB);
  h16_t* w_qkvb = WBASE;
  h16_t* w_outb = w_qkvb + 786432;
  h16_t* ckw0b  = w_outb + 262144;
  h16_t* ckw1b  = ckw0b + 196608;
  h16_t* ckw2b  = ckw1b + 262144;
  h16_t* cvw0b  = ckw2b + 262144;
  h16_t* cvw1b  = cvw0b + 196608;
  h16_t* cvw2b  = cvw1b + 262144;
  h16_t* nl_wb  = cvw2b + 262144;
  h16_t* T0   = (h16_t*)d_out;            // d_out lower 8MB (scratch, ATTN)
  h16_t* T1   = (h16_t*)d_out + 4194304;  // d_out upper 8MB (scratch, ckh)
  h16_t* XB   = S5;
  h16_t* ATTN = T0;

  const dim3 blk(256);
  // 0. MERGED cvt || colnorm p1
  {
    CvtArgs a;
    const float* srcs[10] = {x, w_qkv, w_out, ckw0, ckw1, ckw2, cvw0, cvw1, cvw2, nl_w};
    h16_t* dsts[10] = {XB, w_qkvb, w_outb, ckw0b, ckw1b, ckw2b, cvw0b, cvw1b, cvw2b, nl_wb};
    const int ns[10] = {4194304, 786432, 262144, 196608, 262144, 262144, 196608, 262144, 262144, 262144};
    int cum = 0;
    for (int i = 0; i < 10; ++i) {
      a.src[i] = srcs[i]; a.dst[i] = dsts[i]; a.start4[i] = cum; cum += ns[i] / 4;
    }
    a.total4 = cum;
    a.nblk_cvt = (cum + 383) / 384;
    a.c0 = ck; a.c1 = cv; a.part = part;
    k_cvt_p1<<<a.nblk_cvt + 1024, 384, 0, stream>>>(a);
  }

  // 1. colnorm p2 (+zero part2) + apply
  k_cn_ck_p2<<<dim3(8, 2), 384, 0, stream>>>(part, inv1, part2);
  k_norm_ck<<<dim3(8192, 2), 384, 0, stream>>>(ck, cv, inv1, T0, S0);

  // 2. MERGED g0 || qkv
  {
    Leaky2Args g = {T0, ckw0b, ckb0, T1, S0, cvw0b, cvb0, S1};
    k_g0_qkv<<<5120, blk, 0, stream>>>(g, XB, w_qkvb, S2, S3, S4);
  }

  // 3. g1
  {
    Leaky2Args g = {T1, ckw1b, ckb1, T0, S1, cvw1b, cvb1, S0};
    k_gemm_leaky2<512, 0, 0><<<dim3(128, 8, 2), blk, 0, stream>>>(g);
  }

  // 4. g2: ck -> ckh (T1, bhnd), cv -> cvT (S1, bhdn)
  {
    Leaky2Args g = {T0, ckw2b, ckb2, T1, S0, cvw2b, cvb2, S1};
    k_gemm_leaky2<512, 1, 2><<<dim3(128, 8, 2), blk, 0, stream>>>(g);
  }

  // 5. merged attention z=2 (K+V LDS staging); z=1 accumulates part2
  k_attn4<<<dim3(64, 8, 2), blk, 0, stream>>>(S2, S3, S4, ATTN, T1, S1, S5, part2);

  // 6. rm inverse norms + apply: S5 -> S0
  k_rm_p2b<<<8, 512, 0, stream>>>(part2, inv1);
  k_norm_rm<<<8192, 512, 0, stream>>>(S5, inv1, S0);
  // 7. GEMM+GELU+combine with attn -> S1
  k_gemm_nl<<<dim3(128, 8), blk, 0, stream>>>(S0, nl_wb, nl_b, ATTN, subr, S1);
  // 8. final projection -> d_out (f32)
  k_gemm_out<<<dim3(128, 8), blk, 0, stream>>>(S1, w_outb, b_out, (float*)d_out);
}

// Round 11
// 337.974 us; speedup vs baseline: 1.1578x; 1.0142x over previous
//
#include <hip/hip_runtime.h>
#include <hip/hip_fp16.h>
#include <math.h>

typedef _Float16 h16_t;
typedef __attribute__((ext_vector_type(4))) _Float16 h16x4;
typedef __attribute__((ext_vector_type(8))) _Float16 h16x8;
typedef __attribute__((ext_vector_type(4))) float f32x4;

static_assert(sizeof(h16_t) == 2, "f16 size");

__device__ __forceinline__ f32x4 mfma16(h16x8 a, h16x8 b, f32x4 c) {
  return __builtin_amdgcn_mfma_f32_16x16x32_f16(a, b, c, 0, 0, 0);
}

// ---------------------------------------------------------------------------
// MERGED: fused f32->f16 conversion (10 segments) || ck/cv colnorm phase 1.
// ---------------------------------------------------------------------------
struct CvtArgs {
  const float* src[10];
  h16_t* dst[10];
  int start4[10];
  int total4;
  int nblk_cvt;
  const float* c0;
  const float* c1;
  float* part;
};

__global__ __launch_bounds__(384) void k_cvt_p1(CvtArgs a) {
  const int bid = blockIdx.x;
  if (bid < a.nblk_cvt) {  // --- cvt path ---
    const int i4 = bid * 384 + threadIdx.x;
    if (i4 >= a.total4) return;
    int seg = 0;
#pragma unroll
    for (int t = 1; t < 10; ++t) seg += (i4 >= a.start4[t]) ? 1 : 0;
    const int off = (i4 - a.start4[seg]) * 4;
    const float4 v = *(const float4*)(a.src[seg] + off);
    h16x4 o;
    o[0] = (h16_t)v.x; o[1] = (h16_t)v.y; o[2] = (h16_t)v.z; o[3] = (h16_t)v.w;
    *(h16x4*)(a.dst[seg] + off) = o;
  } else {  // --- cn_ck_p1 path ---
    const int rid = bid - a.nblk_cvt;
    const int b = rid & 7, ch = (rid >> 3) & 63, z = rid >> 9;
    const int f = threadIdx.x;
    const float* c = z ? a.c1 : a.c0;
    const int h = f >> 6, d = f & 63;
    const float* p = c + ((size_t)(b * 6 + h) * 1024 + ch * 16) * 64 + d;
    float s = 0.f;
#pragma unroll
    for (int n = 0; n < 16; ++n) {
      const float v = p[(size_t)n * 64];
      s += v * v;
    }
    a.part[(size_t)z * 196608 + (size_t)(b * 64 + ch) * 384 + f] = s;
  }
}

// ---------------------------------------------------------------------------
// GEMM core v2: W staged through DOUBLE-BUFFERED 128-col LDS segments
// (2x16KB, XOR-swizzled) AND A register-prefetched one segment ahead
// (ar[4], rotated in place: each reload issues before the MFMAs of its ks
// slot, giving it ~a full segment of compute to hide L2 latency — the same
// treatment W already gets). Addresses and summation order identical to the
// verified v1 core -> bit-identical output.
// ---------------------------------------------------------------------------
template <int K>
__device__ __forceinline__ void gemm_run(const h16_t* __restrict__ A,
                                         const h16_t* __restrict__ W,
                                         int m0, int o0, h16_t* wl, f32x4* acc) {
  constexpr int NS = K / 128;
  const int lane = threadIdx.x & 63;
  const int l15 = lane & 15;
  const int quad = lane >> 4;
  int sr[4], sc[4], sd[4];
#pragma unroll
  for (int i = 0; i < 4; ++i) {
    const int id = threadIdx.x + i * 256;
    const int row = id >> 4, c = id & 15;
    sr[i] = row;
    sc[i] = c * 8;
    sd[i] = (row * 16 + (c ^ (row & 7))) * 8;
  }
  const h16_t* ap = A + (size_t)(m0 + l15) * K + quad * 8;
  h16x8 wr[4], ar[4];
#pragma unroll
  for (int i = 0; i < 4; ++i)
    wr[i] = *(const h16x8*)(W + (size_t)(o0 + sr[i]) * K + sc[i]);
#pragma unroll
  for (int ks = 0; ks < 4; ++ks) ar[ks] = *(const h16x8*)(ap + ks * 32);
#pragma unroll
  for (int i = 0; i < 4; ++i) *(h16x8*)(wl + sd[i]) = wr[i];
  __syncthreads();
#pragma unroll
  for (int sg = 0; sg < NS; ++sg) {
    if (sg + 1 < NS) {  // prefetch next W segment (global -> regs)
#pragma unroll
      for (int i = 0; i < 4; ++i)
        wr[i] = *(const h16x8*)(W + (size_t)(o0 + sr[i]) * K + (sg + 1) * 128 + sc[i]);
    }
    const h16_t* wp = wl + (sg & 1) * 8192;
#pragma unroll
    for (int ks = 0; ks < 4; ++ks) {
      const h16x8 af = ar[ks];
      if (sg + 1 < NS)  // reload this ks slot for the next segment NOW;
        ar[ks] = *(const h16x8*)(ap + (sg + 1) * 128 + ks * 32);
#pragma unroll
      for (int j = 0; j < 4; ++j) {
        h16x8 wf = *(const h16x8*)(
            wp + (size_t)((j * 16 + l15) * 16 + ((ks * 4 + quad) ^ (l15 & 7))) * 8);
        acc[j] = mfma16(af, wf, acc[j]);
      }
    }
    if (sg + 1 < NS) {  // store prefetched W into the other buffer
      h16_t* wn = wl + ((sg + 1) & 1) * 8192;
#pragma unroll
      for (int i = 0; i < 4; ++i) *(h16x8*)(wn + sd[i]) = wr[i];
    }
    __syncthreads();
  }
}

#define EPILOGUE_SETUP()                            \
  const int wv = threadIdx.x >> 6;                  \
  const int lane = threadIdx.x & 63;                \
  const int l15 = lane & 15;                        \
  const int quad = lane >> 4;                       \
  const int m0 = blockIdx.x * 64 + wv * 16;         \
  const int o0 = blockIdx.y * 64;                   \
  f32x4 acc[4];                                     \
  for (int j = 0; j < 4; ++j) acc[j] = f32x4{0.f, 0.f, 0.f, 0.f};

struct Leaky2Args {
  const h16_t* A0; const h16_t* W0; const float* b0; h16_t* Y0;
  const h16_t* A1; const h16_t* W1; const float* b1; h16_t* Y1;
};

// LeakyReLU GEMM, z-merged. LAYOUT: 0 row-major; 1 (b,h,n,d); 2 (b,h,d,n)
template <int K, int L0, int L1>
__global__ __launch_bounds__(256) void k_gemm_leaky2(Leaky2Args g) {
  __shared__ h16_t wl[2 * 8192];
  const int zz = blockIdx.z;
  const h16_t* A = zz ? g.A1 : g.A0;
  const h16_t* W = zz ? g.W1 : g.W0;
  const float* bias = zz ? g.b1 : g.b0;
  h16_t* Y = zz ? g.Y1 : g.Y0;
  EPILOGUE_SETUP();
  gemm_run<K>(A, W, m0, o0, wl, acc);
  const int LAYOUT = zz ? L1 : L0;
#pragma unroll
  for (int j = 0; j < 4; ++j)
#pragma unroll
    for (int r = 0; r < 4; ++r) {
      const int o = o0 + j * 16 + l15;
      const int m = m0 + quad * 4 + r;
      float v = acc[j][r] + bias[o];
      v = v > 0.f ? v : 0.2f * v;
      if (LAYOUT == 0) {
        Y[(size_t)m * 512 + o] = (h16_t)v;
      } else {
        const int b = m >> 10, n = m & 1023;
        const int h = o >> 6, d = o & 63;
        if (LAYOUT == 1)
          Y[((size_t)(b * 8 + h) * 1024 + n) * 64 + d] = (h16_t)v;
        else
          Y[((size_t)(b * 8 + h) * 64 + d) * 1024 + n] = (h16_t)v;
      }
    }
}

// ---------------------------------------------------------------------------
// MERGED g0 + qkv (verified Round 6 structure).
// ---------------------------------------------------------------------------
__global__ __launch_bounds__(256) void k_g0_qkv(
    Leaky2Args g, const h16_t* __restrict__ X, const h16_t* __restrict__ Wq,
    h16_t* __restrict__ qb, h16_t* __restrict__ kb, h16_t* __restrict__ vT) {
  __shared__ h16_t wl[2 * 8192];
  const int bid = blockIdx.x;
  const int wv = threadIdx.x >> 6;
  const int lane = threadIdx.x & 63;
  const int l15 = lane & 15;
  const int quad = lane >> 4;
  f32x4 acc[4];
#pragma unroll
  for (int j = 0; j < 4; ++j) acc[j] = f32x4{0.f, 0.f, 0.f, 0.f};

  if (bid < 2048) {
    const int zz = bid >> 10;
    const int m0 = (bid & 127) * 64 + wv * 16;
    const int o0 = ((bid >> 7) & 7) * 64;
    const h16_t* A = zz ? g.A1 : g.A0;
    const h16_t* W = zz ? g.W1 : g.W0;
    const float* bias = zz ? g.b1 : g.b0;
    h16_t* Y = zz ? g.Y1 : g.Y0;
    gemm_run<384>(A, W, m0, o0, wl, acc);
#pragma unroll
    for (int j = 0; j < 4; ++j)
#pragma unroll
      for (int r = 0; r < 4; ++r) {
        const int o = o0 + j * 16 + l15;
        const int m = m0 + quad * 4 + r;
        float v = acc[j][r] + bias[o];
        v = v > 0.f ? v : 0.2f * v;
        Y[(size_t)m * 512 + o] = (h16_t)v;
      }
  } else {
    const int q = bid - 2048;
    const int m0 = (q & 127) * 64 + wv * 16;
    const int o0 = (q >> 7) * 64;
    gemm_run<512>(X, Wq, m0, o0, wl, acc);
#pragma unroll
    for (int j = 0; j < 4; ++j)
#pragma unroll
      for (int r = 0; r < 4; ++r) {
        const int o = o0 + j * 16 + l15;
        const int m = m0 + quad * 4 + r;
        const int b = m >> 10, n = m & 1023;
        const int oo = o & 511, h = oo >> 6, d = oo & 63;
        const size_t bh = (size_t)(b * 8 + h);
        const h16_t v = (h16_t)acc[j][r];
        if (o < 512)
          qb[(bh * 1024 + n) * 64 + d] = v;
        else if (o < 1024)
          kb[(bh * 1024 + n) * 64 + d] = v;
        else
          vT[(bh * 64 + d) * 1024 + n] = v;
      }
  }
}

// nl-MLP GEMM: gelu + combine with attn
__global__ __launch_bounds__(256) void k_gemm_nl(
    const h16_t* __restrict__ A, const h16_t* __restrict__ W,
    const float* __restrict__ bias, const h16_t* __restrict__ attn,
    const float* __restrict__ subr, h16_t* __restrict__ Y) {
  __shared__ h16_t wl[2 * 8192];
  EPILOGUE_SETUP();
  gemm_run<512>(A, W, m0, o0, wl, acc);
#pragma unroll
  for (int j = 0; j < 4; ++j)
#pragma unroll
    for (int r = 0; r < 4; ++r) {
      const int o = o0 + j * 16 + l15;
      const int m = m0 + quad * 4 + r;
      const float v = acc[j][r] + bias[o];
      const float g = 0.5f * v * (1.f + erff(v * 0.70710678118654752f));
      const float res = (float)attn[(size_t)m * 512 + o] - g * subr[o];
      Y[(size_t)m * 512 + o] = (h16_t)res;
    }
}

// final projection (f32 output)
__global__ __launch_bounds__(256) void k_gemm_out(
    const h16_t* __restrict__ A, const h16_t* __restrict__ W,
    const float* __restrict__ bias, float* __restrict__ Y) {
  __shared__ h16_t wl[2 * 8192];
  EPILOGUE_SETUP();
  gemm_run<512>(A, W, m0, o0, wl, acc);
#pragma unroll
  for (int j = 0; j < 4; ++j)
#pragma unroll
    for (int r = 0; r < 4; ++r) {
      const int o = o0 + j * 16 + l15;
      const int m = m0 + quad * 4 + r;
      Y[(size_t)m * 512 + o] = acc[j][r] + bias[o];
    }
}

// ---------------------------------------------------------------------------
// Attention (R10-exact, verified at 63.7 us): z=2, bh-major grid for XCD
// locality, K AND V double-buffered in LDS, MFMA l-sum, sq-fold on z=1.
// ---------------------------------------------------------------------------
__global__ __launch_bounds__(256) void k_attn4(
    const h16_t* __restrict__ q,
    const h16_t* __restrict__ k0, const h16_t* __restrict__ v0, h16_t* __restrict__ out0,
    const h16_t* __restrict__ k1, const h16_t* __restrict__ v1, h16_t* __restrict__ out1,
    float* __restrict__ part2) {
  const int wv = threadIdx.x >> 6;
  const int lane = threadIdx.x & 63;
  const int l15 = lane & 15;
  const int quad = lane >> 4;
  const int bh = blockIdx.x, b = bh >> 3, h = bh & 7;
  const h16_t* kb = (blockIdx.z ? k1 : k0) + (size_t)bh * 65536;
  const h16_t* vb = (blockIdx.z ? v1 : v0) + (size_t)bh * 65536;
  h16_t* out = blockIdx.z ? out1 : out0;

  __shared__ h16_t kls[2 * 4096];  // 2 x 8 KB
  __shared__ h16_t vls[2 * 4096];  // 2 x 8 KB

  const int q0r = blockIdx.y * 128 + wv * 32;
  h16x8 qa[2][2];
#pragma unroll
  for (int t = 0; t < 2; ++t)
#pragma unroll
    for (int s = 0; s < 2; ++s)
      qa[t][s] = *(const h16x8*)(q + ((size_t)bh * 1024 + q0r + t * 16 + l15) * 64 + s * 32 + quad * 8);

  h16x8 ones;
#pragma unroll
  for (int j = 0; j < 8; ++j) ones[j] = (h16_t)1.f;

  int ksrc[2], vsrc[2], ldst[2];
#pragma unroll
  for (int i = 0; i < 2; ++i) {
    const int L = threadIdx.x + i * 256;
    const int row = L >> 3, cs = L & 7;
    const int key = ((row & 3) << 1) | ((row >> 3) & 1);
    const int c = cs ^ key;
    ksrc[i] = row * 64 + c * 8;
    vsrc[i] = row * 1024 + c * 8;
    ldst[i] = L * 8;
  }

  int kfo[2][4], vfo[2][4];
#pragma unroll
  for (int s = 0; s < 2; ++s)
#pragma unroll
    for (int nt = 0; nt < 4; ++nt) {
      const int r = (nt & 1) * 32 + (l15 >> 2) * 8 + (nt >> 1) * 4 + (l15 & 3);
      const int kk = ((r & 3) << 1) | ((r >> 3) & 1);
      kfo[s][nt] = (r * 8 + ((s * 4 + quad) ^ kk)) * 8;
      const int d = nt * 16 + l15;
      const int kd = ((d & 3) << 1) | ((d >> 3) & 1);
      vfo[s][nt] = (d * 8 + ((s * 4 + quad) ^ kd)) * 8;
    }

  f32x4 oaT[2][4];
#pragma unroll
  for (int t = 0; t < 2; ++t)
#pragma unroll
    for (int j = 0; j < 4; ++j) oaT[t][j] = f32x4{0.f, 0.f, 0.f, 0.f};
  f32x4 lacc[2];
#pragma unroll
  for (int t = 0; t < 2; ++t) lacc[t] = f32x4{0.f, 0.f, 0.f, 0.f};

  h16x8 kr[2], vr[2];
#pragma unroll
  for (int i = 0; i < 2; ++i) {
    kr[i] = *(const h16x8*)(kb + ksrc[i]);
    vr[i] = *(const h16x8*)(vb + vsrc[i]);
  }
#pragma unroll
  for (int i = 0; i < 2; ++i) {
    *(h16x8*)(kls + ldst[i]) = kr[i];
    *(h16x8*)(vls + ldst[i]) = vr[i];
  }
  __syncthreads();

  for (int mt = 0; mt < 16; ++mt) {
    const int cur = (mt & 1) * 4096;
    if (mt < 15) {
      const int mm1 = (mt + 1) * 64;
#pragma unroll
      for (int i = 0; i < 2; ++i) {
        kr[i] = *(const h16x8*)(kb + mm1 * 64 + ksrc[i]);
        vr[i] = *(const h16x8*)(vb + mm1 + vsrc[i]);
      }
    }

    f32x4 sfT[2][4];
#pragma unroll
    for (int t = 0; t < 2; ++t)
#pragma unroll
      for (int j = 0; j < 4; ++j) sfT[t][j] = f32x4{0.f, 0.f, 0.f, 0.f};
#pragma unroll
    for (int s = 0; s < 2; ++s)
#pragma unroll
      for (int nt = 0; nt < 4; ++nt) {
        h16x8 kf = *(const h16x8*)(kls + cur + kfo[s][nt]);
        sfT[0][nt] = mfma16(kf, qa[0][s], sfT[0][nt]);
        sfT[1][nt] = mfma16(kf, qa[1][s], sfT[1][nt]);
      }
    int pk[2][4][2];
#pragma unroll
    for (int t = 0; t < 2; ++t)
#pragma unroll
      for (int nt = 0; nt < 4; ++nt) {
        const float e0 = __expf(sfT[t][nt][0] * 0.125f);
        const float e1 = __expf(sfT[t][nt][1] * 0.125f);
        const float e2 = __expf(sfT[t][nt][2] * 0.125f);
        const float e3 = __expf(sfT[t][nt][3] * 0.125f);
        pk[t][nt][0] = __builtin_bit_cast(int, __builtin_amdgcn_cvt_pkrtz(e0, e1));
        pk[t][nt][1] = __builtin_bit_cast(int, __builtin_amdgcn_cvt_pkrtz(e2, e3));
      }
#pragma unroll
    for (int s = 0; s < 2; ++s) {
      int4 b0 = {pk[0][s][0], pk[0][s][1], pk[0][s + 2][0], pk[0][s + 2][1]};
      int4 b1 = {pk[1][s][0], pk[1][s][1], pk[1][s + 2][0], pk[1][s + 2][1]};
      h16x8 bf0 = __builtin_bit_cast(h16x8, b0);
      h16x8 bf1 = __builtin_bit_cast(h16x8, b1);
      lacc[0] = mfma16(ones, bf0, lacc[0]);
      lacc[1] = mfma16(ones, bf1, lacc[1]);
#pragma unroll
      for (int nt = 0; nt < 4; ++nt) {
        h16x8 vf = *(const h16x8*)(vls + cur + vfo[s][nt]);
        oaT[0][nt] = mfma16(vf, bf0, oaT[0][nt]);
        oaT[1][nt] = mfma16(vf, bf1, oaT[1][nt]);
      }
    }

    if (mt < 15) {
      const int nxt = ((mt + 1) & 1) * 4096;
#pragma unroll
      for (int i = 0; i < 2; ++i) {
        *(h16x8*)(kls + nxt + ldst[i]) = kr[i];
        *(h16x8*)(vls + nxt + ldst[i]) = vr[i];
      }
    }
    __syncthreads();
  }

  const bool SQ = blockIdx.z != 0;
  float sq[4][4];
  if (SQ) {
#pragma unroll
    for (int nt = 0; nt < 4; ++nt)
#pragma unroll
      for (int r = 0; r < 4; ++r) sq[nt][r] = 0.f;
  }
#pragma unroll
  for (int t = 0; t < 2; ++t) {
    const float iv = 1.f / lacc[t][0];
    h16_t* obase = out + ((size_t)b * 1024 + q0r + t * 16 + l15) * 512 + h * 64 + quad * 4;
#pragma unroll
    for (int nt = 0; nt < 4; ++nt) {
      h16x4 o;
#pragma unroll
      for (int r = 0; r < 4; ++r) {
        const float v = oaT[t][nt][r] * iv;
        o[r] = (h16_t)v;
        if (SQ) sq[nt][r] += v * v;
      }
      *(h16x4*)(obase + nt * 16) = o;
    }
  }
  if (SQ) {
#pragma unroll
    for (int nt = 0; nt < 4; ++nt)
#pragma unroll
      for (int r = 0; r < 4; ++r) {
        float s = sq[nt][r];
        s += __shfl_xor(s, 1);
        s += __shfl_xor(s, 2);
        s += __shfl_xor(s, 4);
        s += __shfl_xor(s, 8);
        if (l15 == 0)
          atomicAdd(&part2[b * 512 + h * 64 + nt * 16 + quad * 4 + r], s);
      }
  }
}

// ---------------------------------------------------------------------------
// Norm helpers
// ---------------------------------------------------------------------------
__global__ __launch_bounds__(384) void k_cn_ck_p2(const float* __restrict__ part,
                                                  float* __restrict__ inv,
                                                  float* __restrict__ part2) {
  const int b = blockIdx.x, z = blockIdx.y, f = threadIdx.x;
  if (z == 0) {  // zero part2 for this iteration's attn-ctx accumulation
    for (int t = f; t < 512; t += 384) part2[b * 512 + t] = 0.f;
  }
  float s = 0.f;
#pragma unroll 8
  for (int ch = 0; ch < 64; ++ch)
    s += part[(size_t)z * 196608 + (size_t)(b * 64 + ch) * 384 + f];
  inv[z * 3072 + b * 384 + f] = 1.f / fmaxf(sqrtf(s), 1e-12f);
}

__global__ __launch_bounds__(384) void k_norm_ck(const float* __restrict__ c0,
                                                 const float* __restrict__ c1,
                                                 const float* __restrict__ inv,
                                                 h16_t* __restrict__ y0,
                                                 h16_t* __restrict__ y1) {
  const int bn = blockIdx.x, z = blockIdx.y, f = threadIdx.x;
  const float* c = z ? c1 : c0;
  h16_t* out = z ? y1 : y0;
  const int b = bn >> 10, n = bn & 1023;
  const int h = f >> 6, d = f & 63;
  out[(size_t)bn * 384 + f] =
      (h16_t)(c[((size_t)(b * 6 + h) * 1024 + n) * 64 + d] * inv[z * 3072 + b * 384 + f]);
}

// norm_rm with rm_p2b folded in: recompute inv from part2 inline (same f32
// ops, deterministic -> bit-identical to the two-kernel version).
__global__ __launch_bounds__(512) void k_norm_rm(const h16_t* __restrict__ a,
                                                 const float* __restrict__ part2,
                                                 h16_t* __restrict__ out) {
  const int bn = blockIdx.x, f = threadIdx.x;
  const int b = bn >> 10;
  const float inv = 1.f / fmaxf(sqrtf(part2[b * 512 + f]), 1e-12f);
  out[(size_t)bn * 512 + f] = (h16_t)((float)a[(size_t)bn * 512 + f] * inv);
}

// ---------------------------------------------------------------------------
// Schedule v17 (= verified v16 + A-reg-prefetch GEMM core + rm_p2b fold):
//  0. MERGED: cvt {x->S5, weights->WB} || colnorm p1 -> part
//  1. p2 -> inv1 (+zero part2); norm (ck->T0, cv->S0)
//  2. MERGED: g0 {T0->T1, S0->S1} || qkv {S5 -> Q:S2, K:S3, vT:S4}
//  3. g1: T1->T0, S1->S0
//  4. g2: T0->T1 bhnd (ckh), S0->S1 bhdn (cvT)
//  5. attn z=2 (bh-major): z0 (S2,S3,S4)->ATTN(T0); z1 (S2,T1,S1)->S5 + sq->part2
//  6. norm_rm (inv inline from part2): S5 -> S0
//  7. nl GEMM: S0 + ATTN(T0) -> S1
//  8. out GEMM: S1 -> d_out (f32)
// ---------------------------------------------------------------------------
extern "C" void kernel_launch(void* const* d_in, const int* in_sizes, int n_in,
                              void* d_out, int out_size, void* d_ws, size_t ws_size,
                              hipStream_t stream) {
  (void)in_sizes; (void)n_in; (void)out_size; (void)ws_size;
  const float* x     = (const float*)d_in[0];
  const float* ck    = (const float*)d_in[1];
  const float* cv    = (const float*)d_in[2];
  const float* w_qkv = (const float*)d_in[3];
  const float* w_out = (const float*)d_in[4];
  const float* b_out = (const float*)d_in[5];
  const float* ckw0  = (const float*)d_in[6];
  const float* ckb0  = (const float*)d_in[7];
  const float* ckw1  = (const float*)d_in[8];
  const float* ckb1  = (const float*)d_in[9];
  const float* ckw2  = (const float*)d_in[10];
  const float* ckb2  = (const float*)d_in[11];
  const float* cvw0  = (const float*)d_in[12];
  const float* cvb0  = (const float*)d_in[13];
  const float* cvw1  = (const float*)d_in[14];
  const float* cvb1  = (const float*)d_in[15];
  const float* cvw2  = (const float*)d_in[16];
  const float* cvb2  = (const float*)d_in[17];
  const float* nl_w  = (const float*)d_in[18];
  const float* nl_b  = (const float*)d_in[19];
  const float* subr  = (const float*)d_in[20];

  const size_t MB = 1024 * 1024;
  char* p = (char*)d_ws;
  float* inv1 = (float*)p;                          // 24 KB used of 64 KB
  float* part = (float*)(p + 64 * 1024);            // 1.5 MB (colnorm partials)
  float* part2 = (float*)(p + 1600 * 1024);         // 16 KB (rm partials)
  h16_t* S0 = (h16_t*)(p + 2 * MB + 0 * 8 * MB);
  h16_t* S1 = (h16_t*)(p + 2 * MB + 1 * 8 * MB);
  h16_t* S2 = (h16_t*)(p + 2 * MB + 2 * 8 * MB);  // Q
  h16_t* S3 = (h16_t*)(p + 2 * MB + 3 * 8 * MB);  // K_self
  h16_t* S4 = (h16_t*)(p + 2 * MB + 4 * 8 * MB);  // vT_self
  h16_t* S5 = (h16_t*)(p + 2 * MB + 5 * 8 * MB);  // XB, later outc
  h16_t* WBASE = (h16_t*)(p + 50 * MB);
  h16_t* w_qkvb = WBASE;
  h16_t* w_outb = w_qkvb + 786432;
  h16_t* ckw0b  = w_outb + 262144;
  h16_t* ckw1b  = ckw0b + 196608;
  h16_t* ckw2b  = ckw1b + 262144;
  h16_t* cvw0b  = ckw2b + 262144;
  h16_t* cvw1b  = cvw0b + 196608;
  h16_t* cvw2b  = cvw1b + 262144;
  h16_t* nl_wb  = cvw2b + 262144;
  h16_t* T0   = (h16_t*)d_out;            // d_out lower 8MB (scratch, ATTN)
  h16_t* T1   = (h16_t*)d_out + 4194304;  // d_out upper 8MB (scratch, ckh)
  h16_t* XB   = S5;
  h16_t* ATTN = T0;

  const dim3 blk(256);
  // 0. MERGED cvt || colnorm p1
  {
    CvtArgs a;
    const float* srcs[10] = {x, w_qkv, w_out, ckw0, ckw1, ckw2, cvw0, cvw1, cvw2, nl_w};
    h16_t* dsts[10] = {XB, w_qkvb, w_outb, ckw0b, ckw1b, ckw2b, cvw0b, cvw1b, cvw2b, nl_wb};
    const int ns[10] = {4194304, 786432, 262144, 196608, 262144, 262144, 196608, 262144, 262144, 262144};
    int cum = 0;
    for (int i = 0; i < 10; ++i) {
      a.src[i] = srcs[i]; a.dst[i] = dsts[i]; a.start4[i] = cum; cum += ns[i] / 4;
    }
    a.total4 = cum;
    a.nblk_cvt = (cum + 383) / 384;
    a.c0 = ck; a.c1 = cv; a.part = part;
    k_cvt_p1<<<a.nblk_cvt + 1024, 384, 0, stream>>>(a);
  }

  // 1. colnorm p2 (+zero part2) + apply
  k_cn_ck_p2<<<dim3(8, 2), 384, 0, stream>>>(part, inv1, part2);
  k_norm_ck<<<dim3(8192, 2), 384, 0, stream>>>(ck, cv, inv1, T0, S0);

  // 2. MERGED g0 || qkv
  {
    Leaky2Args g = {T0, ckw0b, ckb0, T1, S0, cvw0b, cvb0, S1};
    k_g0_qkv<<<5120, blk, 0, stream>>>(g, XB, w_qkvb, S2, S3, S4);
  }

  // 3. g1
  {
    Leaky2Args g = {T1, ckw1b, ckb1, T0, S1, cvw1b, cvb1, S0};
    k_gemm_leaky2<512, 0, 0><<<dim3(128, 8, 2), blk, 0, stream>>>(g);
  }

  // 4. g2: ck -> ckh (T1, bhnd), cv -> cvT (S1, bhdn)
  {
    Leaky2Args g = {T0, ckw2b, ckb2, T1, S0, cvw2b, cvb2, S1};
    k_gemm_leaky2<512, 1, 2><<<dim3(128, 8, 2), blk, 0, stream>>>(g);
  }

  // 5. merged attention z=2 (K+V LDS staging); z=1 accumulates part2
  k_attn4<<<dim3(64, 8, 2), blk, 0, stream>>>(S2, S3, S4, ATTN, T1, S1, S5, part2);

  // 6. rm norm (inv inline): S5 -> S0
  k_norm_rm<<<8192, 512, 0, stream>>>(S5, part2, S0);
  // 7. GEMM+GELU+combine with attn -> S1
  k_gemm_nl<<<dim3(128, 8), blk, 0, stream>>>(S0, nl_wb, nl_b, ATTN, subr, S1);
  // 8. final projection -> d_out (f32)
  k_gemm_out<<<dim3(128, 8), blk, 0, stream>>>(S1, w_outb, b_out, (float*)d_out);
}